// Round 1
// baseline (242.526 us; speedup 1.0000x reference)
//
#include <hip/hip_runtime.h>
#include <math.h>

// Problem constants (fixed by setup_inputs)
constexpr int N = 2048;   // batch
constexpr int P = 1024;   // p
constexpr int D = 256;    // d
constexpr float TAU = 18.0f;

// d_out section offsets (floats), in reference return order:
// X_hat, Y_hat, X_box, Y_box, Y_pred  (each N*D)
// S_rec, T_rec, T_pred                (each N*P, contiguous)
constexpr size_t OFF_XHAT  = 0;
constexpr size_t OFF_YHAT  = (size_t)N * D;        // 524288
constexpr size_t OFF_XBOX  = 2 * (size_t)N * D;    // 1048576
constexpr size_t OFF_YBOX  = 3 * (size_t)N * D;    // 1572864
constexpr size_t OFF_YPRED = 4 * (size_t)N * D;    // 2097152
constexpr size_t OFF_SREC  = 5 * (size_t)N * D;    // 2621440

// ---------------------------------------------------------------------------
// GEMM1: C[4096][256] = [S;T] @ A, epilogue writes X_hat/Y_hat + clipped boxes
// 64x64 tile, BK=16, 256 threads, 4x4 micro-tile. grid (64,4) = 256 blocks.
// ---------------------------------------------------------------------------
__global__ __launch_bounds__(256) void gemm1_kernel(
    const float* __restrict__ S, const float* __restrict__ Tm,
    const float* __restrict__ A, float* __restrict__ out) {
  __shared__ float As[16][68];  // [k][m] transposed; 68-stride keeps 16B align
  __shared__ float Bs[16][68];  // [k][n]

  const int t  = threadIdx.x;
  const int m0 = blockIdx.x * 64;
  const int n0 = blockIdx.y * 64;
  const int tm = (t & 15) * 4;
  const int tn = (t >> 4) * 4;

  const int lrow = t >> 2;         // 0..63  (m within tile)
  const int lcol = (t & 3) * 4;    // 0,4,8,12 (k within tile)
  const int gr   = m0 + lrow;
  const float* Lrow = (gr < N) ? (S + (size_t)gr * P)
                               : (Tm + (size_t)(gr - N) * P);
  const int brow = t >> 4;         // 0..15 (k)
  const int bcol = (t & 15) * 4;   // 0..60 (n)

  float acc[4][4] = {};

  for (int k0 = 0; k0 < P; k0 += 16) {
    float4 a4 = *(const float4*)(Lrow + k0 + lcol);
    As[lcol + 0][lrow] = a4.x;
    As[lcol + 1][lrow] = a4.y;
    As[lcol + 2][lrow] = a4.z;
    As[lcol + 3][lrow] = a4.w;
    *(float4*)&Bs[brow][bcol] =
        *(const float4*)(A + (size_t)(k0 + brow) * D + n0 + bcol);
    __syncthreads();
#pragma unroll
    for (int k = 0; k < 16; ++k) {
      float4 av = *(const float4*)&As[k][tm];
      float4 bv = *(const float4*)&Bs[k][tn];
      float am[4] = {av.x, av.y, av.z, av.w};
      float bb[4] = {bv.x, bv.y, bv.z, bv.w};
#pragma unroll
      for (int i = 0; i < 4; ++i)
#pragma unroll
        for (int j = 0; j < 4; ++j)
          acc[i][j] = fmaf(am[i], bb[j], acc[i][j]);
    }
    __syncthreads();
  }

#pragma unroll
  for (int i = 0; i < 4; ++i) {
    const int grow = m0 + tm + i;
    float4 v = make_float4(acc[i][0], acc[i][1], acc[i][2], acc[i][3]);
    float4 c;
    c.x = fminf(fmaxf(v.x, 0.0f), 1.0f);
    c.y = fminf(fmaxf(v.y, 0.0f), 1.0f);
    c.z = fminf(fmaxf(v.z, 0.0f), 1.0f);
    c.w = fminf(fmaxf(v.w, 0.0f), 1.0f);
    const size_t col = (size_t)(n0 + tn);
    if (grow < N) {
      *(float4*)(out + OFF_XHAT + (size_t)grow * D + col) = v;
      *(float4*)(out + OFF_XBOX + (size_t)grow * D + col) = c;
    } else {
      const size_t gy = (size_t)(grow - N);
      *(float4*)(out + OFF_YHAT + gy * D + col) = v;
      *(float4*)(out + OFF_YBOX + gy * D + col) = c;
    }
  }
}

// ---------------------------------------------------------------------------
// Smooth compose: Y_pred[n,j] = (1/tau) * log( sum_i 1/(u[n,i] + v[i,j]) )
//   u = exp(-tau * X_box[n,i]),  v = exp(-tau * sigmoid(rawM[i,j]))
// Block computes 16 (n) x 16 (j) outputs; u/v tiles staged in LDS.
// grid (128, 16), 256 threads.
// ---------------------------------------------------------------------------
__global__ __launch_bounds__(256) void smooth_kernel(
    const float* __restrict__ xbox, const float* __restrict__ rawM,
    float* __restrict__ ypred) {
  __shared__ float us[16][260];   // padded stride: kills bank conflicts
  __shared__ float vs[256][16];

  const int t  = threadIdx.x;
  const int n0 = blockIdx.x * 16;
  const int j0 = blockIdx.y * 16;

  // stage u (with exp applied)
  {
    const int r  = t >> 4;            // 0..15
    const int i0 = (t & 15) * 16;     // 0..240
    const float* src = xbox + (size_t)(n0 + r) * D + i0;
#pragma unroll
    for (int q = 0; q < 16; q += 4) {
      float4 x = *(const float4*)(src + q);
      us[r][i0 + q + 0] = expf(-TAU * x.x);
      us[r][i0 + q + 1] = expf(-TAU * x.y);
      us[r][i0 + q + 2] = expf(-TAU * x.z);
      us[r][i0 + q + 3] = expf(-TAU * x.w);
    }
  }
  // stage v = exp(-tau * sigmoid(rawM)), one full column-strip
  {
    const float* src = rawM + (size_t)t * D + j0;
#pragma unroll
    for (int q = 0; q < 16; q += 4) {
      float4 x = *(const float4*)(src + q);
      vs[t][q + 0] = expf(-TAU / (1.0f + expf(-x.x)));
      vs[t][q + 1] = expf(-TAU / (1.0f + expf(-x.y)));
      vs[t][q + 2] = expf(-TAU / (1.0f + expf(-x.z)));
      vs[t][q + 3] = expf(-TAU / (1.0f + expf(-x.w)));
    }
  }
  __syncthreads();

  const int tn = t & 15;
  const int tj = t >> 4;
  float acc = 0.0f;
#pragma unroll 8
  for (int i = 0; i < D; ++i) {
    acc += 1.0f / (us[tn][i] + vs[i][tj]);
  }
  ypred[(size_t)(n0 + tn) * D + (j0 + tj)] = (1.0f / TAU) * logf(acc);
}

// ---------------------------------------------------------------------------
// GEMM2: C[6144][1024] = [X_hat; Y_hat; Y_pred] @ B -> S_rec,T_rec,T_pred
// 128x128 tile, BK=8, 256 threads, 8x8 micro-tile. grid (48,8) = 384 blocks.
// LHS rows 0..4095 are contiguous (X_hat,Y_hat); rows 4096+ come from Y_pred.
// Output sections are contiguous, so rec + row*P covers all three.
// ---------------------------------------------------------------------------
__global__ __launch_bounds__(256) void gemm2_kernel(
    const float* __restrict__ dout, const float* __restrict__ B,
    float* __restrict__ rec) {
  __shared__ float As[8][132];
  __shared__ float Bs[8][132];

  const int t  = threadIdx.x;
  const int m0 = blockIdx.x * 128;
  const int n0 = blockIdx.y * 128;
  const int tm = (t & 15) * 8;
  const int tn = (t >> 4) * 8;

  const int lrow = t >> 1;          // 0..127
  const int lcol = (t & 1) * 4;     // 0 or 4
  const int gr   = m0 + lrow;
  const float* Lrow = (gr < 2 * N)
                          ? (dout + (size_t)gr * D)
                          : (dout + OFF_YPRED + (size_t)(gr - 2 * N) * D);
  const int brow = t >> 5;          // 0..7
  const int bcol = (t & 31) * 4;    // 0..124

  float acc[8][8] = {};

  for (int k0 = 0; k0 < D; k0 += 8) {
    float4 a4 = *(const float4*)(Lrow + k0 + lcol);
    As[lcol + 0][lrow] = a4.x;
    As[lcol + 1][lrow] = a4.y;
    As[lcol + 2][lrow] = a4.z;
    As[lcol + 3][lrow] = a4.w;
    *(float4*)&Bs[brow][bcol] =
        *(const float4*)(B + (size_t)(k0 + brow) * P + n0 + bcol);
    __syncthreads();
#pragma unroll
    for (int k = 0; k < 8; ++k) {
      float a[8], b[8];
      *(float4*)&a[0] = *(const float4*)&As[k][tm];
      *(float4*)&a[4] = *(const float4*)&As[k][tm + 4];
      *(float4*)&b[0] = *(const float4*)&Bs[k][tn];
      *(float4*)&b[4] = *(const float4*)&Bs[k][tn + 4];
#pragma unroll
      for (int i = 0; i < 8; ++i)
#pragma unroll
        for (int j = 0; j < 8; ++j)
          acc[i][j] = fmaf(a[i], b[j], acc[i][j]);
    }
    __syncthreads();
  }

#pragma unroll
  for (int i = 0; i < 8; ++i) {
    const size_t row = (size_t)(m0 + tm + i) * P + (n0 + tn);
    *(float4*)(rec + row)     = make_float4(acc[i][0], acc[i][1], acc[i][2], acc[i][3]);
    *(float4*)(rec + row + 4) = make_float4(acc[i][4], acc[i][5], acc[i][6], acc[i][7]);
  }
}

// ---------------------------------------------------------------------------
extern "C" void kernel_launch(void* const* d_in, const int* in_sizes, int n_in,
                              void* d_out, int out_size, void* d_ws,
                              size_t ws_size, hipStream_t stream) {
  const float* S    = (const float*)d_in[0];
  const float* T    = (const float*)d_in[1];
  const float* A    = (const float*)d_in[2];
  const float* rawM = (const float*)d_in[3];
  const float* B    = (const float*)d_in[4];
  float* out = (float*)d_out;

  // 1) X_hat/Y_hat (+ X_box/Y_box)
  gemm1_kernel<<<dim3(64, 4), 256, 0, stream>>>(S, T, A, out);
  // 2) Y_pred from X_box and rawM
  smooth_kernel<<<dim3(128, 16), 256, 0, stream>>>(out + OFF_XBOX, rawM,
                                                   out + OFF_YPRED);
  // 3) S_rec/T_rec/T_pred
  gemm2_kernel<<<dim3(48, 8), 256, 0, stream>>>(out, B, out + OFF_SREC);
}

// Round 2
// 158.747 us; speedup vs baseline: 1.5278x; 1.5278x over previous
//
#include <hip/hip_runtime.h>
#include <math.h>

constexpr int N = 2048;   // batch
constexpr int P = 1024;   // p
constexpr int D = 256;    // d
constexpr float TAU = 18.0f;

constexpr size_t OFF_XHAT  = 0;
constexpr size_t OFF_YHAT  = (size_t)N * D;
constexpr size_t OFF_XBOX  = 2 * (size_t)N * D;
constexpr size_t OFF_YBOX  = 3 * (size_t)N * D;
constexpr size_t OFF_YPRED = 4 * (size_t)N * D;
constexpr size_t OFF_SREC  = 5 * (size_t)N * D;

// workspace byte offsets
constexpr size_t WS_ATH = 0;          // At hi  [256][1024] bf16 (as short)
constexpr size_t WS_ATL = 524288;     // At lo
constexpr size_t WS_BTH = 1048576;    // Bt hi  [1024][256] bf16
constexpr size_t WS_BTL = 1572864;    // Bt lo
constexpr size_t WS_V   = 2097152;    // V [256][256] f32
constexpr size_t WS_U   = 2359296;    // U [2048][256] f32

typedef short bhalf8 __attribute__((ext_vector_type(8)));
typedef float f32x4  __attribute__((ext_vector_type(4)));

__device__ inline short f2bf(float f) {
  union { float f; unsigned u; } x; x.f = f;
  unsigned r = (x.u + 0x7FFFu + ((x.u >> 16) & 1u)) >> 16;
  return (short)r;
}
__device__ inline float bf2f(short h) {
  union { unsigned u; float f; } x; x.u = ((unsigned)(unsigned short)h) << 16;
  return x.f;
}

// ---------------------------------------------------------------------------
// prep: V[i][j] = exp(-tau * sigmoid(rawM[i][j]))  (64K elems)
// ---------------------------------------------------------------------------
__global__ __launch_bounds__(256) void prep_v_kernel(
    const float* __restrict__ rawM, float* __restrict__ V) {
  const int idx = (blockIdx.x * 256 + threadIdx.x) * 4;
  float4 x = *(const float4*)(rawM + idx);
  float4 o;
  o.x = expf(-TAU / (1.0f + expf(-x.x)));
  o.y = expf(-TAU / (1.0f + expf(-x.y)));
  o.z = expf(-TAU / (1.0f + expf(-x.z)));
  o.w = expf(-TAU / (1.0f + expf(-x.w)));
  *(float4*)(V + idx) = o;
}

// ---------------------------------------------------------------------------
// prep: transpose + hi/lo bf16 split.  src[R][C] f32 -> dh/dl [C][R] bf16.
// grid (R/32, C/32), 256 threads.
// ---------------------------------------------------------------------------
__global__ __launch_bounds__(256) void transpose_hilo_kernel(
    const float* __restrict__ src, short* __restrict__ dh,
    short* __restrict__ dl, int R, int C) {
  __shared__ __align__(16) float tile[32][36];
  const int t = threadIdx.x;
  const int r0 = blockIdx.x * 32, c0 = blockIdx.y * 32;
  {
    const int tr = t >> 3, tc4 = (t & 7) * 4;
    float4 x = *(const float4*)(src + (size_t)(r0 + tr) * C + c0 + tc4);
    *(float4*)&tile[tr][tc4] = x;
  }
  __syncthreads();
  {
    const int tc = t >> 3, tr4 = (t & 7) * 4;
    short4 h, l;
    float f0 = tile[tr4 + 0][tc];
    float f1 = tile[tr4 + 1][tc];
    float f2 = tile[tr4 + 2][tc];
    float f3 = tile[tr4 + 3][tc];
    h.x = f2bf(f0); l.x = f2bf(f0 - bf2f(h.x));
    h.y = f2bf(f1); l.y = f2bf(f1 - bf2f(h.y));
    h.z = f2bf(f2); l.z = f2bf(f2 - bf2f(h.z));
    h.w = f2bf(f3); l.w = f2bf(f3 - bf2f(h.w));
    *(short4*)(dh + (size_t)(c0 + tc) * R + r0 + tr4) = h;
    *(short4*)(dl + (size_t)(c0 + tc) * R + r0 + tr4) = l;
  }
}

// ---------------------------------------------------------------------------
// GEMM1 (MFMA): C[4096][256] = [S;T] @ A  via split-bf16 (hh+hl+lh+ll).
// BM=64 BN=64 BK=32, 256 thr (4 waves, each a 32x32 sub-tile of 2x2 frags).
// Epilogue: X_hat/Y_hat, X_box/Y_box, U = exp(-tau*X_box).
// grid (64, 4).
// ---------------------------------------------------------------------------
__global__ __launch_bounds__(256) void gemm1_mfma(
    const float* __restrict__ S, const float* __restrict__ Tm,
    const short* __restrict__ Ath, const short* __restrict__ Atl,
    float* __restrict__ out, float* __restrict__ U) {
  __shared__ __align__(16) short As_h[64][40];
  __shared__ __align__(16) short As_l[64][40];
  __shared__ __align__(16) short Bs_h[64][40];
  __shared__ __align__(16) short Bs_l[64][40];

  const int t = threadIdx.x;
  const int m0 = blockIdx.x * 64, n0 = blockIdx.y * 64;

  // staging: 4 consecutive lanes cover one row's 32 k's (64B segments)
  const int arow = t >> 2;          // 0..63
  const int koct = (t & 3) * 8;     // 0,8,16,24
  const int grow = m0 + arow;
  const float* Lrow = (grow < N) ? (S + (size_t)grow * P)
                                 : (Tm + (size_t)(grow - N) * P);
  const short* Bh_row = Ath + (size_t)(n0 + arow) * P;
  const short* Bl_row = Atl + (size_t)(n0 + arow) * P;

  // compute ids
  const int l = t & 63, w = t >> 6;
  const int wr = (w >> 1) * 32, wc = (w & 1) * 32;
  const int fr = l & 15;            // frag row (A) / col (B,C)
  const int ko = (l >> 4) * 8;      // k-octet within frag
  const int rq = (l >> 4) * 4;      // C/D row base

  f32x4 acc[2][2];
#pragma unroll
  for (int i = 0; i < 2; ++i)
#pragma unroll
    for (int j = 0; j < 2; ++j) acc[i][j] = (f32x4){0.f, 0.f, 0.f, 0.f};

  float4 a0 = *(const float4*)(Lrow + koct);
  float4 a1 = *(const float4*)(Lrow + koct + 4);
  bhalf8 bh = *(const bhalf8*)(Bh_row + koct);
  bhalf8 bl = *(const bhalf8*)(Bl_row + koct);

  for (int ks = 0; ks < P / 32; ++ks) {
    __syncthreads();
    {
      float af[8] = {a0.x, a0.y, a0.z, a0.w, a1.x, a1.y, a1.z, a1.w};
      bhalf8 ah, al;
#pragma unroll
      for (int q = 0; q < 8; ++q) {
        short h = f2bf(af[q]);
        ah[q] = h;
        al[q] = f2bf(af[q] - bf2f(h));
      }
      *(bhalf8*)&As_h[arow][koct] = ah;
      *(bhalf8*)&As_l[arow][koct] = al;
      *(bhalf8*)&Bs_h[arow][koct] = bh;
      *(bhalf8*)&Bs_l[arow][koct] = bl;
    }
    __syncthreads();
    if (ks + 1 < P / 32) {          // prefetch next tile (hidden under MFMA)
      const int kn = (ks + 1) * 32 + koct;
      a0 = *(const float4*)(Lrow + kn);
      a1 = *(const float4*)(Lrow + kn + 4);
      bh = *(const bhalf8*)(Bh_row + kn);
      bl = *(const bhalf8*)(Bl_row + kn);
    }
    bhalf8 avh[2], avl[2], bvh[2], bvl[2];
#pragma unroll
    for (int mi = 0; mi < 2; ++mi) {
      avh[mi] = *(const bhalf8*)&As_h[wr + mi * 16 + fr][ko];
      avl[mi] = *(const bhalf8*)&As_l[wr + mi * 16 + fr][ko];
      bvh[mi] = *(const bhalf8*)&Bs_h[wc + mi * 16 + fr][ko];
      bvl[mi] = *(const bhalf8*)&Bs_l[wc + mi * 16 + fr][ko];
    }
#pragma unroll
    for (int mi = 0; mi < 2; ++mi)
#pragma unroll
      for (int ni = 0; ni < 2; ++ni) {
        acc[mi][ni] = __builtin_amdgcn_mfma_f32_16x16x32_bf16(avh[mi], bvh[ni], acc[mi][ni], 0, 0, 0);
        acc[mi][ni] = __builtin_amdgcn_mfma_f32_16x16x32_bf16(avh[mi], bvl[ni], acc[mi][ni], 0, 0, 0);
        acc[mi][ni] = __builtin_amdgcn_mfma_f32_16x16x32_bf16(avl[mi], bvh[ni], acc[mi][ni], 0, 0, 0);
        acc[mi][ni] = __builtin_amdgcn_mfma_f32_16x16x32_bf16(avl[mi], bvl[ni], acc[mi][ni], 0, 0, 0);
      }
  }

#pragma unroll
  for (int mi = 0; mi < 2; ++mi)
#pragma unroll
    for (int ni = 0; ni < 2; ++ni) {
      const int col = n0 + wc + ni * 16 + fr;
#pragma unroll
      for (int r = 0; r < 4; ++r) {
        const int row = m0 + wr + mi * 16 + rq + r;
        const float v = acc[mi][ni][r];
        const float c = fminf(fmaxf(v, 0.0f), 1.0f);
        if (row < N) {
          out[OFF_XHAT + (size_t)row * D + col] = v;
          out[OFF_XBOX + (size_t)row * D + col] = c;
          U[(size_t)row * D + col] = expf(-TAU * c);
        } else {
          const size_t ry = (size_t)(row - N);
          out[OFF_YHAT + ry * D + col] = v;
          out[OFF_YBOX + ry * D + col] = c;
        }
      }
    }
}

// ---------------------------------------------------------------------------
// smooth: Y_pred[n][j] = (1/tau) * log( sum_i rcp(U[n][i] + V[i][j]) )
// block tile 32n x 64j, micro 2n x 4j; U transposed into LDS, V from L2.
// grid (64, 4), 256 threads.
// ---------------------------------------------------------------------------
__global__ __launch_bounds__(256) void smooth_kernel(
    const float* __restrict__ U, const float* __restrict__ V,
    float* __restrict__ ypred) {
  __shared__ float us[256][33];   // us[i][n]
  const int t = threadIdx.x;
  const int n0 = blockIdx.x * 32, j0 = blockIdx.y * 64;

  {
    const int sr = t & 31;            // n-row within tile
    const int si = (t >> 5) * 32;     // i-chunk
    const float* up = U + (size_t)(n0 + sr) * D + si;
#pragma unroll
    for (int q = 0; q < 32; q += 4) {
      float4 x = *(const float4*)(up + q);
      us[si + q + 0][sr] = x.x;
      us[si + q + 1][sr] = x.y;
      us[si + q + 2][sr] = x.z;
      us[si + q + 3][sr] = x.w;
    }
  }
  __syncthreads();

  const int jg = (t & 15) * 4;      // j offset
  const int nn = (t >> 4) * 2;      // n offset
  const float* vp = V + j0 + jg;

  float acc[2][4] = {};
#pragma unroll 4
  for (int i = 0; i < D; ++i) {
    const float u0 = us[i][nn];
    const float u1 = us[i][nn + 1];
    float4 v4 = *(const float4*)(vp + (size_t)i * D);
    acc[0][0] += __builtin_amdgcn_rcpf(u0 + v4.x);
    acc[0][1] += __builtin_amdgcn_rcpf(u0 + v4.y);
    acc[0][2] += __builtin_amdgcn_rcpf(u0 + v4.z);
    acc[0][3] += __builtin_amdgcn_rcpf(u0 + v4.w);
    acc[1][0] += __builtin_amdgcn_rcpf(u1 + v4.x);
    acc[1][1] += __builtin_amdgcn_rcpf(u1 + v4.y);
    acc[1][2] += __builtin_amdgcn_rcpf(u1 + v4.z);
    acc[1][3] += __builtin_amdgcn_rcpf(u1 + v4.w);
  }
#pragma unroll
  for (int pI = 0; pI < 2; ++pI) {
    float4 o;
    o.x = (1.0f / TAU) * logf(acc[pI][0]);
    o.y = (1.0f / TAU) * logf(acc[pI][1]);
    o.z = (1.0f / TAU) * logf(acc[pI][2]);
    o.w = (1.0f / TAU) * logf(acc[pI][3]);
    *(float4*)(ypred + (size_t)(n0 + nn + pI) * D + j0 + jg) = o;
  }
}

// ---------------------------------------------------------------------------
// GEMM2 (MFMA): C[6144][1024] = [X_hat;Y_hat;Y_pred] @ B via split-bf16.
// Same tile structure as gemm1; K=256 (8 k-steps). grid (96, 16).
// ---------------------------------------------------------------------------
__global__ __launch_bounds__(256) void gemm2_mfma(
    const float* __restrict__ dout, const short* __restrict__ Bth,
    const short* __restrict__ Btl, float* __restrict__ rec) {
  __shared__ __align__(16) short As_h[64][40];
  __shared__ __align__(16) short As_l[64][40];
  __shared__ __align__(16) short Bs_h[64][40];
  __shared__ __align__(16) short Bs_l[64][40];

  const int t = threadIdx.x;
  const int m0 = blockIdx.x * 64, n0 = blockIdx.y * 64;

  const int arow = t >> 2;
  const int koct = (t & 3) * 8;
  const int grow = m0 + arow;
  const float* Lrow = (grow < 2 * N)
                          ? (dout + (size_t)grow * D)
                          : (dout + OFF_YPRED + (size_t)(grow - 2 * N) * D);
  const short* Bh_row = Bth + (size_t)(n0 + arow) * D;
  const short* Bl_row = Btl + (size_t)(n0 + arow) * D;

  const int l = t & 63, w = t >> 6;
  const int wr = (w >> 1) * 32, wc = (w & 1) * 32;
  const int fr = l & 15;
  const int ko = (l >> 4) * 8;
  const int rq = (l >> 4) * 4;

  f32x4 acc[2][2];
#pragma unroll
  for (int i = 0; i < 2; ++i)
#pragma unroll
    for (int j = 0; j < 2; ++j) acc[i][j] = (f32x4){0.f, 0.f, 0.f, 0.f};

  float4 a0 = *(const float4*)(Lrow + koct);
  float4 a1 = *(const float4*)(Lrow + koct + 4);
  bhalf8 bh = *(const bhalf8*)(Bh_row + koct);
  bhalf8 bl = *(const bhalf8*)(Bl_row + koct);

  for (int ks = 0; ks < D / 32; ++ks) {
    __syncthreads();
    {
      float af[8] = {a0.x, a0.y, a0.z, a0.w, a1.x, a1.y, a1.z, a1.w};
      bhalf8 ah, al;
#pragma unroll
      for (int q = 0; q < 8; ++q) {
        short h = f2bf(af[q]);
        ah[q] = h;
        al[q] = f2bf(af[q] - bf2f(h));
      }
      *(bhalf8*)&As_h[arow][koct] = ah;
      *(bhalf8*)&As_l[arow][koct] = al;
      *(bhalf8*)&Bs_h[arow][koct] = bh;
      *(bhalf8*)&Bs_l[arow][koct] = bl;
    }
    __syncthreads();
    if (ks + 1 < D / 32) {
      const int kn = (ks + 1) * 32 + koct;
      a0 = *(const float4*)(Lrow + kn);
      a1 = *(const float4*)(Lrow + kn + 4);
      bh = *(const bhalf8*)(Bh_row + kn);
      bl = *(const bhalf8*)(Bl_row + kn);
    }
    bhalf8 avh[2], avl[2], bvh[2], bvl[2];
#pragma unroll
    for (int mi = 0; mi < 2; ++mi) {
      avh[mi] = *(const bhalf8*)&As_h[wr + mi * 16 + fr][ko];
      avl[mi] = *(const bhalf8*)&As_l[wr + mi * 16 + fr][ko];
      bvh[mi] = *(const bhalf8*)&Bs_h[wc + mi * 16 + fr][ko];
      bvl[mi] = *(const bhalf8*)&Bs_l[wc + mi * 16 + fr][ko];
    }
#pragma unroll
    for (int mi = 0; mi < 2; ++mi)
#pragma unroll
      for (int ni = 0; ni < 2; ++ni) {
        acc[mi][ni] = __builtin_amdgcn_mfma_f32_16x16x32_bf16(avh[mi], bvh[ni], acc[mi][ni], 0, 0, 0);
        acc[mi][ni] = __builtin_amdgcn_mfma_f32_16x16x32_bf16(avh[mi], bvl[ni], acc[mi][ni], 0, 0, 0);
        acc[mi][ni] = __builtin_amdgcn_mfma_f32_16x16x32_bf16(avl[mi], bvh[ni], acc[mi][ni], 0, 0, 0);
        acc[mi][ni] = __builtin_amdgcn_mfma_f32_16x16x32_bf16(avl[mi], bvl[ni], acc[mi][ni], 0, 0, 0);
      }
  }

#pragma unroll
  for (int mi = 0; mi < 2; ++mi)
#pragma unroll
    for (int ni = 0; ni < 2; ++ni) {
      const int col = n0 + wc + ni * 16 + fr;
#pragma unroll
      for (int r = 0; r < 4; ++r) {
        const int row = m0 + wr + mi * 16 + rq + r;
        rec[(size_t)row * P + col] = acc[mi][ni][r];
      }
    }
}

// ---------------------------------------------------------------------------
extern "C" void kernel_launch(void* const* d_in, const int* in_sizes, int n_in,
                              void* d_out, int out_size, void* d_ws,
                              size_t ws_size, hipStream_t stream) {
  const float* S    = (const float*)d_in[0];
  const float* T    = (const float*)d_in[1];
  const float* A    = (const float*)d_in[2];
  const float* rawM = (const float*)d_in[3];
  const float* B    = (const float*)d_in[4];
  float* out = (float*)d_out;
  char* ws = (char*)d_ws;

  short* Ath = (short*)(ws + WS_ATH);
  short* Atl = (short*)(ws + WS_ATL);
  short* Bth = (short*)(ws + WS_BTH);
  short* Btl = (short*)(ws + WS_BTL);
  float* V   = (float*)(ws + WS_V);
  float* U   = (float*)(ws + WS_U);

  prep_v_kernel<<<64, 256, 0, stream>>>(rawM, V);
  transpose_hilo_kernel<<<dim3(32, 8), 256, 0, stream>>>(A, Ath, Atl, P, D);
  transpose_hilo_kernel<<<dim3(8, 32), 256, 0, stream>>>(B, Bth, Btl, D, P);
  gemm1_mfma<<<dim3(64, 4), 256, 0, stream>>>(S, T, Ath, Atl, out, U);
  smooth_kernel<<<dim3(64, 4), 256, 0, stream>>>(U, V, out + OFF_YPRED);
  gemm2_mfma<<<dim3(96, 16), 256, 0, stream>>>(out, Bth, Btl, out + OFF_SREC);
}

// Round 3
// 138.713 us; speedup vs baseline: 1.7484x; 1.1444x over previous
//
#include <hip/hip_runtime.h>
#include <math.h>

constexpr int N = 2048;   // batch
constexpr int P = 1024;   // p
constexpr int D = 256;    // d
constexpr float TAU = 18.0f;

constexpr size_t OFF_XHAT  = 0;
constexpr size_t OFF_YHAT  = (size_t)N * D;
constexpr size_t OFF_XBOX  = 2 * (size_t)N * D;
constexpr size_t OFF_YBOX  = 3 * (size_t)N * D;
constexpr size_t OFF_YPRED = 4 * (size_t)N * D;
constexpr size_t OFF_SREC  = 5 * (size_t)N * D;

// workspace byte offsets
constexpr size_t WS_ATH = 0;          // At hi  [256][1024] bf16
constexpr size_t WS_ATL = 524288;     // At lo
constexpr size_t WS_BTH = 1048576;    // Bt hi  [1024][256] bf16
constexpr size_t WS_BTL = 1572864;    // Bt lo
constexpr size_t WS_V   = 2097152;    // V [256][256] f32
constexpr size_t WS_U   = 2359296;    // U [2048][256] f32
constexpr size_t WS_LHH = 4456448;    // LHS hi [6144][256] bf16 (Xh,Yh,Ypred)
constexpr size_t WS_LHL = 7602176;    // LHS lo

typedef short bhalf8 __attribute__((ext_vector_type(8)));
typedef float f32x4  __attribute__((ext_vector_type(4)));

__device__ inline short f2bf(float f) {
  union { float f; unsigned u; } x; x.f = f;
  unsigned r = (x.u + 0x7FFFu + ((x.u >> 16) & 1u)) >> 16;
  return (short)r;
}
__device__ inline float bf2f(short h) {
  union { unsigned u; float f; } x; x.u = ((unsigned)(unsigned short)h) << 16;
  return x.f;
}

// ---------------------------------------------------------------------------
// prep: V[i][j] = exp(-tau * sigmoid(rawM[i][j]))
// ---------------------------------------------------------------------------
__global__ __launch_bounds__(256) void prep_v_kernel(
    const float* __restrict__ rawM, float* __restrict__ V) {
  const int idx = (blockIdx.x * 256 + threadIdx.x) * 4;
  float4 x = *(const float4*)(rawM + idx);
  float4 o;
  o.x = expf(-TAU / (1.0f + expf(-x.x)));
  o.y = expf(-TAU / (1.0f + expf(-x.y)));
  o.z = expf(-TAU / (1.0f + expf(-x.z)));
  o.w = expf(-TAU / (1.0f + expf(-x.w)));
  *(float4*)(V + idx) = o;
}

// ---------------------------------------------------------------------------
// prep: transpose + hi/lo bf16 split.  src[R][C] f32 -> dh/dl [C][R] bf16.
// ---------------------------------------------------------------------------
__global__ __launch_bounds__(256) void transpose_hilo_kernel(
    const float* __restrict__ src, short* __restrict__ dh,
    short* __restrict__ dl, int R, int C) {
  __shared__ __align__(16) float tile[32][36];
  const int t = threadIdx.x;
  const int r0 = blockIdx.x * 32, c0 = blockIdx.y * 32;
  {
    const int tr = t >> 3, tc4 = (t & 7) * 4;
    float4 x = *(const float4*)(src + (size_t)(r0 + tr) * C + c0 + tc4);
    *(float4*)&tile[tr][tc4] = x;
  }
  __syncthreads();
  {
    const int tc = t >> 3, tr4 = (t & 7) * 4;
    short4 h, l;
    float f0 = tile[tr4 + 0][tc];
    float f1 = tile[tr4 + 1][tc];
    float f2 = tile[tr4 + 2][tc];
    float f3 = tile[tr4 + 3][tc];
    h.x = f2bf(f0); l.x = f2bf(f0 - bf2f(h.x));
    h.y = f2bf(f1); l.y = f2bf(f1 - bf2f(h.y));
    h.z = f2bf(f2); l.z = f2bf(f2 - bf2f(h.z));
    h.w = f2bf(f3); l.w = f2bf(f3 - bf2f(h.w));
    *(short4*)(dh + (size_t)(c0 + tc) * R + r0 + tr4) = h;
    *(short4*)(dl + (size_t)(c0 + tc) * R + r0 + tr4) = l;
  }
}

// ---------------------------------------------------------------------------
// GEMM1 (MFMA): C[4096][256] = [S;T] @ A, 3-term split (hh+hl+lh).
// BM=64 BN=64 BK=32, 512 thr = 8 waves (wave tile 16x32), dbuf LDS,
// 1 barrier / k-step. Epilogue: hats, boxes, U, bf16 hi/lo LHS for gemm2.
// grid (64, 4).
// ---------------------------------------------------------------------------
__global__ __launch_bounds__(512) void gemm1_mfma(
    const float* __restrict__ S, const float* __restrict__ Tm,
    const short* __restrict__ Ath, const short* __restrict__ Atl,
    float* __restrict__ out, float* __restrict__ U,
    short* __restrict__ LHh, short* __restrict__ LHl) {
  __shared__ __align__(16) short As_h[2][64][40];
  __shared__ __align__(16) short As_l[2][64][40];
  __shared__ __align__(16) short Bs_h[2][64][40];
  __shared__ __align__(16) short Bs_l[2][64][40];

  const int t  = threadIdx.x;
  const int m0 = blockIdx.x * 64, n0 = blockIdx.y * 64;

  // staging: 8 lanes per row, 4 k each (BK=32)
  const int srow = t >> 3;
  const int sk   = (t & 7) * 4;
  const int grow = m0 + srow;
  const float* Lrow = (grow < N) ? (S + (size_t)grow * P)
                                 : (Tm + (size_t)(grow - N) * P);
  const short* BhR = Ath + (size_t)(n0 + srow) * P;
  const short* BlR = Atl + (size_t)(n0 + srow) * P;

  // compute ids: 8 waves, wave tile 16(m) x 32(n)
  const int l = t & 63, w = t >> 6;
  const int wr = (w & 3) * 16, wc = (w >> 2) * 32;
  const int fr = l & 15, ko8 = (l >> 4) * 8, rq = (l >> 4) * 4;

  f32x4 acc[2];
  acc[0] = (f32x4){0.f, 0.f, 0.f, 0.f};
  acc[1] = (f32x4){0.f, 0.f, 0.f, 0.f};

  float4 pa  = *(const float4*)(Lrow + sk);
  short4 pbh = *(const short4*)(BhR + sk);
  short4 pbl = *(const short4*)(BlR + sk);

#define STAGE1(buf)                                        \
  do {                                                     \
    short4 ah4, al4;                                       \
    ah4.x = f2bf(pa.x); al4.x = f2bf(pa.x - bf2f(ah4.x));  \
    ah4.y = f2bf(pa.y); al4.y = f2bf(pa.y - bf2f(ah4.y));  \
    ah4.z = f2bf(pa.z); al4.z = f2bf(pa.z - bf2f(ah4.z));  \
    ah4.w = f2bf(pa.w); al4.w = f2bf(pa.w - bf2f(ah4.w));  \
    *(short4*)&As_h[buf][srow][sk] = ah4;                  \
    *(short4*)&As_l[buf][srow][sk] = al4;                  \
    *(short4*)&Bs_h[buf][srow][sk] = pbh;                  \
    *(short4*)&Bs_l[buf][srow][sk] = pbl;                  \
  } while (0)

  STAGE1(0);

  for (int ks = 0; ks < 32; ++ks) {
    const int b = ks & 1;
    if (ks < 31) {
      const int kn = (ks + 1) * 32;
      pa  = *(const float4*)(Lrow + kn + sk);
      pbh = *(const short4*)(BhR + kn + sk);
      pbl = *(const short4*)(BlR + kn + sk);
    }
    __syncthreads();
    bhalf8 ahv = *(const bhalf8*)&As_h[b][wr + fr][ko8];
    bhalf8 alv = *(const bhalf8*)&As_l[b][wr + fr][ko8];
#pragma unroll
    for (int ni = 0; ni < 2; ++ni) {
      bhalf8 bhv = *(const bhalf8*)&Bs_h[b][wc + ni * 16 + fr][ko8];
      bhalf8 blv = *(const bhalf8*)&Bs_l[b][wc + ni * 16 + fr][ko8];
      acc[ni] = __builtin_amdgcn_mfma_f32_16x16x32_bf16(ahv, bhv, acc[ni], 0, 0, 0);
      acc[ni] = __builtin_amdgcn_mfma_f32_16x16x32_bf16(ahv, blv, acc[ni], 0, 0, 0);
      acc[ni] = __builtin_amdgcn_mfma_f32_16x16x32_bf16(alv, bhv, acc[ni], 0, 0, 0);
    }
    if (ks < 31) STAGE1((ks + 1) & 1);
  }
#undef STAGE1

#pragma unroll
  for (int ni = 0; ni < 2; ++ni) {
    const int col = n0 + wc + ni * 16 + fr;
#pragma unroll
    for (int r = 0; r < 4; ++r) {
      const int row = m0 + wr + rq + r;
      const float v = acc[ni][r];
      const float c = fminf(fmaxf(v, 0.0f), 1.0f);
      const short h  = f2bf(v);
      const short lo = f2bf(v - bf2f(h));
      LHh[(size_t)row * D + col] = h;
      LHl[(size_t)row * D + col] = lo;
      if (row < N) {
        out[OFF_XHAT + (size_t)row * D + col] = v;
        out[OFF_XBOX + (size_t)row * D + col] = c;
        U[(size_t)row * D + col] = expf(-TAU * c);
      } else {
        const size_t ry = (size_t)(row - N);
        out[OFF_YHAT + ry * D + col] = v;
        out[OFF_YBOX + ry * D + col] = c;
      }
    }
  }
}

// ---------------------------------------------------------------------------
// smooth: Y_pred[n][j] = (1/tau) * log( sum_i rcp(U[n][i] + V[i][j]) )
// 32n x 32j tile, micro 2n x 2j; grid (64, 8), 256 threads.
// Epilogue also writes bf16 hi/lo of Y_pred into LHS rows 4096+.
// ---------------------------------------------------------------------------
__global__ __launch_bounds__(256) void smooth_kernel(
    const float* __restrict__ U, const float* __restrict__ V,
    float* __restrict__ ypred, short* __restrict__ LHh,
    short* __restrict__ LHl) {
  __shared__ float us[256][34];   // us[i][n], pad keeps float2 aligned
  const int t = threadIdx.x;
  const int n0 = blockIdx.x * 32, j0 = blockIdx.y * 32;

  {
    const int sr = t & 31;            // n within tile
    const int si = (t >> 5) * 32;     // i-chunk
    const float* up = U + (size_t)(n0 + sr) * D + si;
#pragma unroll
    for (int q = 0; q < 32; q += 4) {
      float4 x = *(const float4*)(up + q);
      us[si + q + 0][sr] = x.x;
      us[si + q + 1][sr] = x.y;
      us[si + q + 2][sr] = x.z;
      us[si + q + 3][sr] = x.w;
    }
  }
  __syncthreads();

  const int jg = (t & 15) * 2;
  const int nn = (t >> 4) * 2;
  const float* vp = V + j0 + jg;

  float acc00 = 0.f, acc01 = 0.f, acc10 = 0.f, acc11 = 0.f;
#pragma unroll 8
  for (int i = 0; i < D; ++i) {
    float2 u2 = *(const float2*)&us[i][nn];
    float2 v2 = *(const float2*)(vp + (size_t)i * D);
    acc00 += __builtin_amdgcn_rcpf(u2.x + v2.x);
    acc01 += __builtin_amdgcn_rcpf(u2.x + v2.y);
    acc10 += __builtin_amdgcn_rcpf(u2.y + v2.x);
    acc11 += __builtin_amdgcn_rcpf(u2.y + v2.y);
  }

  float a[2][2] = {{acc00, acc01}, {acc10, acc11}};
#pragma unroll
  for (int pI = 0; pI < 2; ++pI) {
    const int row = n0 + nn + pI;
    float2 o;
    o.x = (1.0f / TAU) * logf(a[pI][0]);
    o.y = (1.0f / TAU) * logf(a[pI][1]);
    *(float2*)(ypred + (size_t)row * D + j0 + jg) = o;
    short2 h2, l2;
    h2.x = f2bf(o.x); l2.x = f2bf(o.x - bf2f(h2.x));
    h2.y = f2bf(o.y); l2.y = f2bf(o.y - bf2f(h2.y));
    const size_t lrow = (size_t)(2 * N + row) * D + j0 + jg;
    *(short2*)(LHh + lrow) = h2;
    *(short2*)(LHl + lrow) = l2;
  }
}

// ---------------------------------------------------------------------------
// GEMM2 (MFMA): C[6144][1024] = [X_hat;Y_hat;Y_pred] @ B, 3-term split.
// Same 8-wave dbuf structure as gemm1; all operands pre-split bf16.
// K=256 -> 8 steps. grid (96, 16).
// ---------------------------------------------------------------------------
__global__ __launch_bounds__(512) void gemm2_mfma(
    const short* __restrict__ LHh, const short* __restrict__ LHl,
    const short* __restrict__ Bth, const short* __restrict__ Btl,
    float* __restrict__ rec) {
  __shared__ __align__(16) short As_h[2][64][40];
  __shared__ __align__(16) short As_l[2][64][40];
  __shared__ __align__(16) short Bs_h[2][64][40];
  __shared__ __align__(16) short Bs_l[2][64][40];

  const int t  = threadIdx.x;
  const int m0 = blockIdx.x * 64, n0 = blockIdx.y * 64;

  const int srow = t >> 3;
  const int sk   = (t & 7) * 4;
  const short* AhR = LHh + (size_t)(m0 + srow) * D;
  const short* AlR = LHl + (size_t)(m0 + srow) * D;
  const short* BhR = Bth + (size_t)(n0 + srow) * D;
  const short* BlR = Btl + (size_t)(n0 + srow) * D;

  const int l = t & 63, w = t >> 6;
  const int wr = (w & 3) * 16, wc = (w >> 2) * 32;
  const int fr = l & 15, ko8 = (l >> 4) * 8, rq = (l >> 4) * 4;

  f32x4 acc[2];
  acc[0] = (f32x4){0.f, 0.f, 0.f, 0.f};
  acc[1] = (f32x4){0.f, 0.f, 0.f, 0.f};

  short4 pah = *(const short4*)(AhR + sk);
  short4 pal = *(const short4*)(AlR + sk);
  short4 pbh = *(const short4*)(BhR + sk);
  short4 pbl = *(const short4*)(BlR + sk);

#define STAGE2(buf)                            \
  do {                                         \
    *(short4*)&As_h[buf][srow][sk] = pah;      \
    *(short4*)&As_l[buf][srow][sk] = pal;      \
    *(short4*)&Bs_h[buf][srow][sk] = pbh;      \
    *(short4*)&Bs_l[buf][srow][sk] = pbl;      \
  } while (0)

  STAGE2(0);

  for (int ks = 0; ks < 8; ++ks) {
    const int b = ks & 1;
    if (ks < 7) {
      const int kn = (ks + 1) * 32;
      pah = *(const short4*)(AhR + kn + sk);
      pal = *(const short4*)(AlR + kn + sk);
      pbh = *(const short4*)(BhR + kn + sk);
      pbl = *(const short4*)(BlR + kn + sk);
    }
    __syncthreads();
    bhalf8 ahv = *(const bhalf8*)&As_h[b][wr + fr][ko8];
    bhalf8 alv = *(const bhalf8*)&As_l[b][wr + fr][ko8];
#pragma unroll
    for (int ni = 0; ni < 2; ++ni) {
      bhalf8 bhv = *(const bhalf8*)&Bs_h[b][wc + ni * 16 + fr][ko8];
      bhalf8 blv = *(const bhalf8*)&Bs_l[b][wc + ni * 16 + fr][ko8];
      acc[ni] = __builtin_amdgcn_mfma_f32_16x16x32_bf16(ahv, bhv, acc[ni], 0, 0, 0);
      acc[ni] = __builtin_amdgcn_mfma_f32_16x16x32_bf16(ahv, blv, acc[ni], 0, 0, 0);
      acc[ni] = __builtin_amdgcn_mfma_f32_16x16x32_bf16(alv, bhv, acc[ni], 0, 0, 0);
    }
    if (ks < 7) STAGE2((ks + 1) & 1);
  }
#undef STAGE2

#pragma unroll
  for (int ni = 0; ni < 2; ++ni) {
    const int col = n0 + wc + ni * 16 + fr;
#pragma unroll
    for (int r = 0; r < 4; ++r) {
      const int row = m0 + wr + rq + r;
      rec[(size_t)row * P + col] = acc[ni][r];
    }
  }
}

// ---------------------------------------------------------------------------
extern "C" void kernel_launch(void* const* d_in, const int* in_sizes, int n_in,
                              void* d_out, int out_size, void* d_ws,
                              size_t ws_size, hipStream_t stream) {
  const float* S    = (const float*)d_in[0];
  const float* T    = (const float*)d_in[1];
  const float* A    = (const float*)d_in[2];
  const float* rawM = (const float*)d_in[3];
  const float* B    = (const float*)d_in[4];
  float* out = (float*)d_out;
  char* ws = (char*)d_ws;

  short* Ath = (short*)(ws + WS_ATH);
  short* Atl = (short*)(ws + WS_ATL);
  short* Bth = (short*)(ws + WS_BTH);
  short* Btl = (short*)(ws + WS_BTL);
  float* V   = (float*)(ws + WS_V);
  float* U   = (float*)(ws + WS_U);
  short* LHh = (short*)(ws + WS_LHH);
  short* LHl = (short*)(ws + WS_LHL);

  prep_v_kernel<<<64, 256, 0, stream>>>(rawM, V);
  transpose_hilo_kernel<<<dim3(32, 8), 256, 0, stream>>>(A, Ath, Atl, P, D);
  transpose_hilo_kernel<<<dim3(8, 32), 256, 0, stream>>>(B, Bth, Btl, D, P);
  gemm1_mfma<<<dim3(64, 4), 512, 0, stream>>>(S, T, Ath, Atl, out, U, LHh, LHl);
  smooth_kernel<<<dim3(64, 8), 256, 0, stream>>>(U, V, out + OFF_YPRED, LHh, LHl);
  gemm2_mfma<<<dim3(96, 16), 512, 0, stream>>>(LHh, LHl, Bth, Btl, out + OFF_SREC);
}